// Round 8
// baseline (1721.536 us; speedup 1.0000x reference)
//
#include <hip/hip_runtime.h>
#include <hip/hip_bf16.h>
#include <math.h>

#define N_NODES 50000
#define N_EDGES 1600000
#define E_TOT   3200000
#define NFEAT   512
#define NHID    128
#define NCLASS  40

#define NPB    128                      // nodes per bucket
#define G1BUCK 391                      // graph1 buckets: ceil(50000/128)
#define NODE_OFF2 (G1BUCK * NPB)        // 50048: graph2 node base (bucket-aligned)
#define NBUCK  782                      // total buckets (graph2: 391..781)
#define BCAP   4608                     // slots/bucket (mean 4096, +8 sigma)

__device__ __forceinline__ float bf_lo(unsigned u) { return __uint_as_float(u << 16); }
__device__ __forceinline__ float bf_hi(unsigned u) { return __uint_as_float(u & 0xFFFF0000u); }
__device__ __forceinline__ float bf1(unsigned short v) { return __uint_as_float((unsigned)v << 16); }
__device__ __forceinline__ unsigned short f2bf(float f) {
  __hip_bfloat16 h = __float2bfloat16(f);
  return *(unsigned short*)&h;
}

typedef __attribute__((ext_vector_type(8))) __bf16 bf16x8;
typedef __attribute__((ext_vector_type(4))) float f32x4;

// ---------------- one-time W1 -> bf16 transposed [col][k] ----------------
__global__ __launch_bounds__(256) void prep_w1_kernel(const float* __restrict__ W1,
                                                      unsigned short* __restrict__ W1bT) {
  const int i = blockIdx.x * 256 + threadIdx.x;
  if (i < NFEAT * NHID) {
    const int k = i >> 7, col = i & 127;
    W1bT[col * NFEAT + k] = f2bf(W1[i]);
  }
}

// ---------------- GEMM1 (MFMA): S1b slabs [4][N][32](bf16) = x @ W1 ----------------
#define APAD 80
#define BPAD 72
__global__ __launch_bounds__(256) void gemm1_kernel(const float* __restrict__ A,
                                                    const unsigned short* __restrict__ W1bT,
                                                    unsigned short* __restrict__ Cb) {
  __shared__ unsigned short As[128 * APAD / 2];
  __shared__ unsigned short Bt[128 * BPAD / 2];
  const int tid = threadIdx.x;
  const int lane = tid & 63;
  const int wave = tid >> 6;
  const int wm = wave >> 1, wn = wave & 1;
  const int rowBase = blockIdx.x * 128;

  f32x4 acc[4][4];
#pragma unroll
  for (int i = 0; i < 4; ++i)
#pragma unroll
    for (int j = 0; j < 4; ++j) acc[i][j] = (f32x4){0.f, 0.f, 0.f, 0.f};

  const int kb = (lane >> 4) * 8;
  const int rA = tid >> 1;
  const int cA = (tid & 1) * 4;
  int garow = rowBase + rA; if (garow > N_NODES - 1) garow = N_NODES - 1;
  const float4* __restrict__ Arow = (const float4*)&A[(size_t)garow * NFEAT];
  const int colB = tid >> 1;
  const int halfB = (tid & 1) * 16;

  for (int k0 = 0; k0 < NFEAT; k0 += 32) {
#pragma unroll
    for (int j = 0; j < 4; ++j) {
      const float4 v = Arow[(k0 >> 2) + cA + j];
      ushort4 o;
      o.x = f2bf(v.x); o.y = f2bf(v.y); o.z = f2bf(v.z); o.w = f2bf(v.w);
      *(ushort4*)((char*)As + rA * APAD + (cA + j) * 8) = o;
    }
    {
      const int4 v0 = *(const int4*)&W1bT[colB * NFEAT + k0 + halfB];
      const int4 v1 = *(const int4*)&W1bT[colB * NFEAT + k0 + halfB + 8];
      *(int4*)((char*)Bt + colB * BPAD + halfB * 2) = v0;
      *(int4*)((char*)Bt + colB * BPAD + halfB * 2 + 16) = v1;
    }
    __syncthreads();
    bf16x8 af[4], bfr[4];
#pragma unroll
    for (int i = 0; i < 4; ++i) {
      const int row = wm * 64 + i * 16 + (lane & 15);
      af[i] = *(const bf16x8*)((const char*)As + row * APAD + kb * 2);
    }
#pragma unroll
    for (int j = 0; j < 4; ++j) {
      const int col = wn * 64 + j * 16 + (lane & 15);
      bfr[j] = *(const bf16x8*)((const char*)Bt + col * BPAD + kb * 2);
    }
#pragma unroll
    for (int i = 0; i < 4; ++i)
#pragma unroll
      for (int j = 0; j < 4; ++j)
        acc[i][j] = __builtin_amdgcn_mfma_f32_16x16x32_bf16(af[i], bfr[j], acc[i][j], 0, 0, 0);
    __syncthreads();
  }
#pragma unroll
  for (int i = 0; i < 4; ++i) {
#pragma unroll
    for (int q = 0; q < 4; ++q) {
      const int grow = rowBase + wm * 64 + i * 16 + (lane >> 4) * 4 + q;
      if (grow < N_NODES) {
#pragma unroll
        for (int j = 0; j < 4; ++j) {
          const int col = wn * 64 + j * 16 + (lane & 15);
          Cb[((size_t)(col >> 5) * N_NODES + grow) * 32 + (col & 31)] = f2bf(acc[i][j][q]);
        }
      }
    }
  }
}

// ---------------- zero bucket cursors ----------------
__global__ __launch_bounds__(1024) void zero_bcur_kernel(int* __restrict__ bcur) {
  const int t = threadIdx.x;
  if (t < NBUCK) bcur[t] = 0;
}

// ---------------- bucketize: 1024 thr x 8 = 8192 edges/WG -> 391 WGs ----------------
// entry: {key = src | dstloc<<16, w_fp32}
__global__ __launch_bounds__(1024) void bucketize_kernel(const int* __restrict__ ei1,
                                                         const float* __restrict__ ew1,
                                                         const int* __restrict__ ei2,
                                                         const float* __restrict__ ew2,
                                                         int* __restrict__ bcur,
                                                         int2* __restrict__ bkt) {
  __shared__ int hist[NBUCK];
  __shared__ int base[NBUCK];
  const int tid = threadIdx.x;
  if (tid < NBUCK) hist[tid] = 0;
  __syncthreads();
  const int e0g = (blockIdx.x * 1024 + tid) * 8;
  const bool valid = e0g < E_TOT;
  int key[8]; float wv[8]; int bb[8]; int rank[8];
  if (valid) {
    const int g = (e0g >= N_EDGES);
    const int e0 = e0g - (g ? N_EDGES : 0);
    const int* __restrict__ ei = g ? ei2 : ei1;
    const float* __restrict__ ew = g ? ew2 : ew1;
    const int node_off = g ? NODE_OFF2 : 0;
    const int4 s0 = *(const int4*)&ei[e0];
    const int4 s1 = *(const int4*)&ei[e0 + 4];
    const int4 d0 = *(const int4*)&ei[N_EDGES + e0];
    const int4 d1 = *(const int4*)&ei[N_EDGES + e0 + 4];
    const float4 w0 = *(const float4*)&ew[e0];
    const float4 w1 = *(const float4*)&ew[e0 + 4];
    const int srcs[8] = {s0.x, s0.y, s0.z, s0.w, s1.x, s1.y, s1.z, s1.w};
    const int dsts[8] = {d0.x, d0.y, d0.z, d0.w, d1.x, d1.y, d1.z, d1.w};
    const float ws[8] = {w0.x, w0.y, w0.z, w0.w, w1.x, w1.y, w1.z, w1.w};
#pragma unroll
    for (int j = 0; j < 8; ++j) {
      const int dg = dsts[j] + node_off;
      const int b = dg >> 7;                    // NPB=128
      bb[j] = b;
      key[j] = srcs[j] | ((dg & 127) << 16);
      wv[j] = ws[j];
      rank[j] = atomicAdd(&hist[b], 1);
    }
  }
  __syncthreads();
  if (tid < NBUCK) {
    const int c = hist[tid];
    base[tid] = c ? atomicAdd(&bcur[tid], c) : 0;
  }
  __syncthreads();
  if (valid) {
#pragma unroll
    for (int j = 0; j < 8; ++j) {
      const int pos = base[bb[j]] + rank[j];
      if (pos < BCAP)
        bkt[(size_t)bb[j] * BCAP + pos] = make_int2(key[j], __float_as_int(wv[j]));
    }
  }
}

// ---------------- agg1 from buckets: LDS 128x32 accum, XCD-sliced col-groups ----------------
// block = (bucket b<391, group g); H1 = relu(b1 + sum w*S1b[src])
__global__ __launch_bounds__(256) void agg1_bucket_kernel(const int* __restrict__ bcur,
                                                          const int2* __restrict__ bkt,
                                                          const unsigned short* __restrict__ S1b,
                                                          const float* __restrict__ b1,
                                                          float* __restrict__ H1) {
  __shared__ float lacc[NPB * 32];   // 16 KB
  const int tid = threadIdx.x;
  const int g = blockIdx.x & 3;
  const int b = blockIdx.x >> 2;
  const int n0 = b * NPB;
  for (int i = tid; i < NPB * 32; i += 256) lacc[i] = 0.f;
  __syncthreads();
  const int cnt = min(bcur[b], BCAP);
  const int2* __restrict__ ebase = bkt + (size_t)b * BCAP;
  const unsigned* __restrict__ slab32 = (const unsigned*)(S1b + (size_t)g * N_NODES * 32);
  const int wave = tid >> 6, lane = tid & 63;
  const int sub = lane >> 4, l = lane & 15;
  int i = wave * 4 + sub;
  // 16 edges in flight per block iteration, unrolled x2
  for (; i + 16 < cnt; i += 32) {
    const int2 qa = ebase[i];
    const int2 qb = ebase[i + 16];
    const unsigned ua = slab32[((qa.x & 0xFFFF) << 4) | l];
    const unsigned ub = slab32[((qb.x & 0xFFFF) << 4) | l];
    const float wa = __int_as_float(qa.y);
    const float wb = __int_as_float(qb.y);
    const int da = ((qa.x >> 16) & 127) * 32 + 2 * l;
    const int db = ((qb.x >> 16) & 127) * 32 + 2 * l;
    atomicAdd(&lacc[da], wa * bf_lo(ua));
    atomicAdd(&lacc[da + 1], wa * bf_hi(ua));
    atomicAdd(&lacc[db], wb * bf_lo(ub));
    atomicAdd(&lacc[db + 1], wb * bf_hi(ub));
  }
  for (; i < cnt; i += 16) {
    const int2 q = ebase[i];
    const unsigned u = slab32[((q.x & 0xFFFF) << 4) | l];
    const float w = __int_as_float(q.y);
    const int d = ((q.x >> 16) & 127) * 32 + 2 * l;
    atomicAdd(&lacc[d], w * bf_lo(u));
    atomicAdd(&lacc[d + 1], w * bf_hi(u));
  }
  __syncthreads();
  for (int k = tid; k < NPB * 32; k += 256) {
    const int n = n0 + (k >> 5);
    if (n < N_NODES) {
      const int c = k & 31;
      H1[(size_t)n * NHID + g * 32 + c] = fmaxf(lacc[k] + b1[g * 32 + c], 0.f);
    }
  }
}

// ---------------- GEMM2: S2b[M,40](bf16) = H1[M,128] @ W2[128,40] ----------------
__global__ __launch_bounds__(320) void gemm2_kernel(const float* __restrict__ H1,
                                                    const float* __restrict__ W2,
                                                    unsigned short* __restrict__ S2b) {
  __shared__ float Bs[NHID * NCLASS];
  for (int i = threadIdx.x; i < NHID * NCLASS; i += 320) Bs[i] = W2[i];
  __syncthreads();
  const int row = blockIdx.x * 8 + threadIdx.x / NCLASS;
  const int col = threadIdx.x % NCLASS;
  if (row >= N_NODES) return;
  const float4* __restrict__ arow4 = (const float4*)&H1[(size_t)row * NHID];
  float acc = 0.f;
#pragma unroll 8
  for (int k4 = 0; k4 < NHID / 4; ++k4) {
    const float4 a = arow4[k4];
    acc = fmaf(a.x, Bs[(k4 * 4 + 0) * NCLASS + col], acc);
    acc = fmaf(a.y, Bs[(k4 * 4 + 1) * NCLASS + col], acc);
    acc = fmaf(a.z, Bs[(k4 * 4 + 2) * NCLASS + col], acc);
    acc = fmaf(a.w, Bs[(k4 * 4 + 3) * NCLASS + col], acc);
  }
  S2b[(size_t)row * NCLASS + col] = f2bf(acc);
}

// ---------------- agg2 + bias + log_softmax from buckets (graph2: buckets 391..781) ----------------
__global__ __launch_bounds__(256) void agg2_lsm_bucket_kernel(const int* __restrict__ bcur,
                                                              const int2* __restrict__ bkt,
                                                              const unsigned short* __restrict__ S2b,
                                                              const float* __restrict__ b2,
                                                              float* __restrict__ out) {
  __shared__ float lacc[NPB * NCLASS];  // 20 KB
  __shared__ float b2s[NCLASS];
  const int tid = threadIdx.x;
  const int b = G1BUCK + blockIdx.x;
  const int n0 = blockIdx.x * NPB;
  for (int i = tid; i < NPB * NCLASS; i += 256) lacc[i] = 0.f;
  if (tid < NCLASS) b2s[tid] = b2[tid];
  __syncthreads();
  const int cnt = min(bcur[b], BCAP);
  const int2* __restrict__ ebase = bkt + (size_t)b * BCAP;
  const int wave = tid >> 6, lane = tid & 63;
  if (lane < NCLASS) {
    for (int i = wave; i < cnt; i += 4) {
      const int2 q = ebase[i];
      const int s = q.x & 0xFFFF;
      const int dl = (q.x >> 16) & 127;
      const float w = __int_as_float(q.y);
      const float v = bf1(S2b[s * NCLASS + lane]);
      atomicAdd(&lacc[dl * NCLASS + lane], w * v);
    }
  }
  __syncthreads();
  if (tid < NPB) {
    const int n = n0 + tid;
    if (n < N_NODES) {
      float vv[NCLASS];
      float m = -3.4e38f;
#pragma unroll
      for (int j = 0; j < NCLASS; ++j) {
        vv[j] = lacc[tid * NCLASS + j] + b2s[j];
        m = fmaxf(m, vv[j]);
      }
      float ssum = 0.f;
#pragma unroll
      for (int j = 0; j < NCLASS; ++j) ssum += __expf(vv[j] - m);
      const float lse = m + __logf(ssum);
#pragma unroll
      for (int j = 0; j < NCLASS; ++j) out[(size_t)n * NCLASS + j] = vv[j] - lse;
    }
  }
}

extern "C" void kernel_launch(void* const* d_in, const int* in_sizes, int n_in,
                              void* d_out, int out_size, void* d_ws, size_t ws_size,
                              hipStream_t stream) {
  const float* x   = (const float*)d_in[0];
  const int*   ei1 = (const int*)d_in[2];
  const float* ew1 = (const float*)d_in[3];
  const int*   ei2 = (const int*)d_in[4];
  const float* ew2 = (const float*)d_in[5];
  const float* W1  = (const float*)d_in[6];
  const float* b1  = (const float*)d_in[7];
  const float* W2  = (const float*)d_in[8];
  const float* b2  = (const float*)d_in[9];
  float* out = (float*)d_out;

  // workspace (~71.4 MB), no aliasing: bkt is consumed by BOTH agg kernels
  char* base = (char*)d_ws;
  int2*           bkt  = (int2*)base;                           // [0, 28827648)
  unsigned short* S1b  = (unsigned short*)(base + 28827648);    // 12.8 MB, 4 slabs [g][N][32]
  float*          H1   = (float*)(base + 41627648);             // 25.6 MB
  unsigned short* S2b  = (unsigned short*)(base + 67227648);    // 4 MB
  unsigned short* W1bT = (unsigned short*)(base + 71227648);    // 128 KB
  int*            bcur = (int*)(base + 71358720);               // NBUCK*4

  prep_w1_kernel<<<(NFEAT * NHID + 255) / 256, 256, 0, stream>>>(W1, W1bT);
  gemm1_kernel<<<(N_NODES + 127) / 128, 256, 0, stream>>>(x, W1bT, S1b);

  zero_bcur_kernel<<<1, 1024, 0, stream>>>(bcur);
  bucketize_kernel<<<(E_TOT / 8 + 1023) / 1024, 1024, 0, stream>>>(ei1, ew1, ei2, ew2, bcur, bkt);

  // layer 1 aggregate straight from buckets (+bias+relu)
  agg1_bucket_kernel<<<G1BUCK * 4, 256, 0, stream>>>(bcur, bkt, S1b, b1, H1);

  // layer 2
  gemm2_kernel<<<(N_NODES + 7) / 8, 320, 0, stream>>>(H1, W2, S2b);
  agg2_lsm_bucket_kernel<<<G1BUCK, 256, 0, stream>>>(bcur, bkt, S2b, b2, out);
}

// Round 9
// 232.820 us; speedup vs baseline: 7.3943x; 7.3943x over previous
//
#include <hip/hip_runtime.h>
#include <hip/hip_bf16.h>
#include <math.h>

#define N_NODES 50000
#define N_TOT   100000
#define N_EDGES 1600000
#define E_TOT   3200000
#define NFEAT   512
#define NHID    128
#define NCLASS  40

#define NPB   256                              // nodes per bucket
#define NBUCK ((N_TOT + NPB - 1) / NPB)        // 391
#define BCAP  9216                             // slots/bucket (mean 8184, +11 sigma)

__device__ __forceinline__ float bf_lo(unsigned u) { return __uint_as_float(u << 16); }
__device__ __forceinline__ float bf_hi(unsigned u) { return __uint_as_float(u & 0xFFFF0000u); }
__device__ __forceinline__ unsigned short f2bf(float f) {
  __hip_bfloat16 h = __float2bfloat16(f);
  return *(unsigned short*)&h;
}
__device__ __forceinline__ unsigned short f2h_bits(float f) {
  const _Float16 h = (_Float16)f;
  return __builtin_bit_cast(unsigned short, h);
}
__device__ __forceinline__ float h2f_lo(unsigned p) {  // fp16 in low 16 bits
  const _Float16 h = __builtin_bit_cast(_Float16, (unsigned short)(p & 0xFFFFu));
  return (float)h;
}

typedef __attribute__((ext_vector_type(8))) __bf16 bf16x8;
typedef __attribute__((ext_vector_type(4))) float f32x4;

// ---------------- one-time W1 -> bf16 transposed [col][k] ----------------
__global__ __launch_bounds__(256) void prep_w1_kernel(const float* __restrict__ W1,
                                                      unsigned short* __restrict__ W1bT) {
  const int i = blockIdx.x * 256 + threadIdx.x;
  if (i < NFEAT * NHID) {
    const int k = i >> 7, col = i & 127;
    W1bT[col * NFEAT + k] = f2bf(W1[i]);
  }
}

// ---------------- GEMM1 (MFMA): S1b slabs [4][N][32](bf16) = x @ W1 ----------------
#define APAD 80
#define BPAD 72
__global__ __launch_bounds__(256) void gemm1_kernel(const float* __restrict__ A,
                                                    const unsigned short* __restrict__ W1bT,
                                                    unsigned short* __restrict__ Cb) {
  __shared__ unsigned short As[128 * APAD / 2];
  __shared__ unsigned short Bt[128 * BPAD / 2];
  const int tid = threadIdx.x;
  const int lane = tid & 63;
  const int wave = tid >> 6;
  const int wm = wave >> 1, wn = wave & 1;
  const int rowBase = blockIdx.x * 128;

  f32x4 acc[4][4];
#pragma unroll
  for (int i = 0; i < 4; ++i)
#pragma unroll
    for (int j = 0; j < 4; ++j) acc[i][j] = (f32x4){0.f, 0.f, 0.f, 0.f};

  const int kb = (lane >> 4) * 8;
  const int rA = tid >> 1;
  const int cA = (tid & 1) * 4;
  int garow = rowBase + rA; if (garow > N_NODES - 1) garow = N_NODES - 1;
  const float4* __restrict__ Arow = (const float4*)&A[(size_t)garow * NFEAT];
  const int colB = tid >> 1;
  const int halfB = (tid & 1) * 16;

  for (int k0 = 0; k0 < NFEAT; k0 += 32) {
#pragma unroll
    for (int j = 0; j < 4; ++j) {
      const float4 v = Arow[(k0 >> 2) + cA + j];
      ushort4 o;
      o.x = f2bf(v.x); o.y = f2bf(v.y); o.z = f2bf(v.z); o.w = f2bf(v.w);
      *(ushort4*)((char*)As + rA * APAD + (cA + j) * 8) = o;
    }
    {
      const int4 v0 = *(const int4*)&W1bT[colB * NFEAT + k0 + halfB];
      const int4 v1 = *(const int4*)&W1bT[colB * NFEAT + k0 + halfB + 8];
      *(int4*)((char*)Bt + colB * BPAD + halfB * 2) = v0;
      *(int4*)((char*)Bt + colB * BPAD + halfB * 2 + 16) = v1;
    }
    __syncthreads();
    bf16x8 af[4], bfr[4];
#pragma unroll
    for (int i = 0; i < 4; ++i) {
      const int row = wm * 64 + i * 16 + (lane & 15);
      af[i] = *(const bf16x8*)((const char*)As + row * APAD + kb * 2);
    }
#pragma unroll
    for (int j = 0; j < 4; ++j) {
      const int col = wn * 64 + j * 16 + (lane & 15);
      bfr[j] = *(const bf16x8*)((const char*)Bt + col * BPAD + kb * 2);
    }
#pragma unroll
    for (int i = 0; i < 4; ++i)
#pragma unroll
      for (int j = 0; j < 4; ++j)
        acc[i][j] = __builtin_amdgcn_mfma_f32_16x16x32_bf16(af[i], bfr[j], acc[i][j], 0, 0, 0);
    __syncthreads();
  }
#pragma unroll
  for (int i = 0; i < 4; ++i) {
#pragma unroll
    for (int q = 0; q < 4; ++q) {
      const int grow = rowBase + wm * 64 + i * 16 + (lane >> 4) * 4 + q;
      if (grow < N_NODES) {
#pragma unroll
        for (int j = 0; j < 4; ++j) {
          const int col = wn * 64 + j * 16 + (lane & 15);
          Cb[((size_t)(col >> 5) * N_NODES + grow) * 32 + (col & 31)] = f2bf(acc[i][j][q]);
        }
      }
    }
  }
}

// ---------------- zero bucket cursors ----------------
__global__ __launch_bounds__(1024) void zero_bcur_kernel(int* __restrict__ bcur) {
  const int t = threadIdx.x;
  if (t < NBUCK) bcur[t] = 0;
}

// ---------------- bucketize: 1024 thr x 8 = 8192 edges/WG -> 391 WGs ----------------
__global__ __launch_bounds__(1024) void bucketize_kernel(const int* __restrict__ ei1,
                                                         const float* __restrict__ ew1,
                                                         const int* __restrict__ ei2,
                                                         const float* __restrict__ ew2,
                                                         int* __restrict__ bcur,
                                                         int2* __restrict__ bkt) {
  __shared__ int hist[NBUCK];
  __shared__ int base[NBUCK];
  const int tid = threadIdx.x;
  if (tid < NBUCK) hist[tid] = 0;
  __syncthreads();
  const int e0g = (blockIdx.x * 1024 + tid) * 8;
  const bool valid = e0g < E_TOT;
  int key[8]; float wv[8]; int bb[8]; int rank[8];
  if (valid) {
    const int g = (e0g >= N_EDGES);
    const int e0 = e0g - (g ? N_EDGES : 0);
    const int* __restrict__ ei = g ? ei2 : ei1;
    const float* __restrict__ ew = g ? ew2 : ew1;
    const int node_off = g ? N_NODES : 0;
    const int4 s0 = *(const int4*)&ei[e0];
    const int4 s1 = *(const int4*)&ei[e0 + 4];
    const int4 d0 = *(const int4*)&ei[N_EDGES + e0];
    const int4 d1 = *(const int4*)&ei[N_EDGES + e0 + 4];
    const float4 w0 = *(const float4*)&ew[e0];
    const float4 w1 = *(const float4*)&ew[e0 + 4];
    const int srcs[8] = {s0.x, s0.y, s0.z, s0.w, s1.x, s1.y, s1.z, s1.w};
    const int dsts[8] = {d0.x, d0.y, d0.z, d0.w, d1.x, d1.y, d1.z, d1.w};
    const float ws[8] = {w0.x, w0.y, w0.z, w0.w, w1.x, w1.y, w1.z, w1.w};
#pragma unroll
    for (int j = 0; j < 8; ++j) {
      const int dg = dsts[j] + node_off;
      const int b = dg >> 8;                    // NPB=256
      bb[j] = b;
      key[j] = srcs[j] | ((dg & 255) << 16);    // src:16 | dstloc:8
      wv[j] = ws[j];
      rank[j] = atomicAdd(&hist[b], 1);
    }
  }
  __syncthreads();
  if (tid < NBUCK) {
    const int c = hist[tid];
    base[tid] = c ? atomicAdd(&bcur[tid], c) : 0;
  }
  __syncthreads();
  if (valid) {
#pragma unroll
    for (int j = 0; j < 8; ++j) {
      const int pos = base[bb[j]] + rank[j];
      if (pos < BCAP)
        bkt[(size_t)bb[j] * BCAP + pos] = make_int2(key[j], __float_as_int(wv[j]));
    }
  }
}

// ---------------- scan of 391 bucket counts (one 512-thread block) ----------------
__global__ __launch_bounds__(512) void bucket_scan_kernel(const int* __restrict__ bcur,
                                                          int* __restrict__ bptr,
                                                          int* __restrict__ row_ptr) {
  __shared__ int s[512];
  const int tid = threadIdx.x;
  const int v = (tid < NBUCK) ? bcur[tid] : 0;
  s[tid] = v;
  __syncthreads();
  for (int d = 1; d < 512; d <<= 1) {
    const int t = (tid >= d) ? s[tid - d] : 0;
    __syncthreads();
    s[tid] += t;
    __syncthreads();
  }
  if (tid < NBUCK) bptr[tid] = s[tid] - v;
  if (tid == 0) row_ptr[N_TOT] = E_TOT;
}

// ---------------- finalize: one WG per bucket, packed 4B CSR entries ----------------
// ent word = w_fp16 (low16) | src (high16)
__global__ __launch_bounds__(256) void finalize_kernel(const int2* __restrict__ bkt,
                                                       const int* __restrict__ bcur,
                                                       const int* __restrict__ bptr,
                                                       int* __restrict__ row_ptr,
                                                       unsigned* __restrict__ ent) {
  __shared__ int hist[NPB];
  __shared__ int scanb[NPB];
  const int b = blockIdx.x;
  const int tid = threadIdx.x;
  const int cnt = bcur[b];
  const int gbase = bptr[b];
  hist[tid] = 0;
  __syncthreads();
  const int2* __restrict__ src = bkt + (size_t)b * BCAP;
  for (int i = tid; i < cnt; i += 256) atomicAdd(&hist[src[i].x >> 16], 1);
  __syncthreads();
  const int v = hist[tid];
  scanb[tid] = v;
  __syncthreads();
  for (int d = 1; d < 256; d <<= 1) {
    const int t = (tid >= d) ? scanb[tid - d] : 0;
    __syncthreads();
    scanb[tid] += t;
    __syncthreads();
  }
  const int excl = scanb[tid] - v;
  const int node = b * NPB + tid;
  if (node < N_TOT) row_ptr[node] = gbase + excl;
  hist[tid] = gbase + excl;  // global-position cursor
  __syncthreads();
  for (int i = tid; i < cnt; i += 256) {
    const int2 q = src[i];
    const int pos = atomicAdd(&hist[q.x >> 16], 1);
    ent[pos] = (unsigned)f2h_bits(__int_as_float(q.y)) | ((unsigned)(q.x & 0xFFFF) << 16);
  }
}

// ---------------- agg1 (pull, XCD-sliced, 32-bit offsets, unroll 8) ----------------
// block b: col-group g=b&3 (slab g, 32 cols); wave = 4 nodes x 16 lanes x float2
__global__ __launch_bounds__(256) void agg1_kernel(const int* __restrict__ rp,
                                                   const unsigned* __restrict__ ent,
                                                   const unsigned short* __restrict__ S1b,
                                                   const float* __restrict__ b1,
                                                   float* __restrict__ H1) {
  const int tid = threadIdx.x;
  const int wave = tid >> 6, lane = tid & 63;
  const int sub = lane >> 4, l = lane & 15;
  const int g = blockIdx.x & 3;
  const int n = (blockIdx.x >> 2) * 16 + wave * 4 + sub;
  if (n >= N_NODES) return;
  const unsigned* __restrict__ slab32 = (const unsigned*)(S1b + (size_t)g * N_NODES * 32);
  float2 acc = *(const float2*)&b1[g * 32 + (l << 1)];
  int e = rp[n];
  const int end = rp[n + 1];
  for (; e + 8 <= end; e += 8) {
    unsigned p[8];
#pragma unroll
    for (int j = 0; j < 8; ++j) p[j] = ent[e + j];
    unsigned u[8];
#pragma unroll
    for (int j = 0; j < 8; ++j) u[j] = slab32[((p[j] >> 16) << 4) | l];
#pragma unroll
    for (int j = 0; j < 8; ++j) {
      const float w = h2f_lo(p[j]);
      acc.x = fmaf(w, bf_lo(u[j]), acc.x);
      acc.y = fmaf(w, bf_hi(u[j]), acc.y);
    }
  }
  for (; e < end; ++e) {
    const unsigned p = ent[e];
    const unsigned u = slab32[((p >> 16) << 4) | l];
    const float w = h2f_lo(p);
    acc.x = fmaf(w, bf_lo(u), acc.x);
    acc.y = fmaf(w, bf_hi(u), acc.y);
  }
  acc.x = fmaxf(acc.x, 0.f);
  acc.y = fmaxf(acc.y, 0.f);
  *(float2*)&H1[(size_t)n * NHID + g * 32 + (l << 1)] = acc;
}

// ---------------- GEMM2: S2b[M,40](bf16) = H1[M,128] @ W2[128,40] ----------------
__global__ __launch_bounds__(320) void gemm2_kernel(const float* __restrict__ H1,
                                                    const float* __restrict__ W2,
                                                    unsigned short* __restrict__ S2b) {
  __shared__ float Bs[NHID * NCLASS];
  for (int i = threadIdx.x; i < NHID * NCLASS; i += 320) Bs[i] = W2[i];
  __syncthreads();
  const int row = blockIdx.x * 8 + threadIdx.x / NCLASS;
  const int col = threadIdx.x % NCLASS;
  if (row >= N_NODES) return;
  const float4* __restrict__ arow4 = (const float4*)&H1[(size_t)row * NHID];
  float acc = 0.f;
#pragma unroll 8
  for (int k4 = 0; k4 < NHID / 4; ++k4) {
    const float4 a = arow4[k4];
    acc = fmaf(a.x, Bs[(k4 * 4 + 0) * NCLASS + col], acc);
    acc = fmaf(a.y, Bs[(k4 * 4 + 1) * NCLASS + col], acc);
    acc = fmaf(a.z, Bs[(k4 * 4 + 2) * NCLASS + col], acc);
    acc = fmaf(a.w, Bs[(k4 * 4 + 3) * NCLASS + col], acc);
  }
  S2b[(size_t)row * NCLASS + col] = f2bf(acc);
}

// ---------------- agg2 + bias + log_softmax fused (32-bit offsets) ----------------
__global__ __launch_bounds__(256) void agg2_lsm_kernel(const int* __restrict__ rp,
                                                       const unsigned* __restrict__ ent,
                                                       const unsigned short* __restrict__ S2b,
                                                       const float* __restrict__ b2,
                                                       float* __restrict__ out) {
  const int wave = threadIdx.x >> 6;
  const int lane = threadIdx.x & 63;
  const int n = blockIdx.x * 4 + wave;
  if (n >= N_NODES) return;
  const bool act = lane < NCLASS;
  const int cl = act ? lane : 0;
  float acc = act ? b2[cl] : 0.f;
  int e = rp[N_NODES + n];
  const int end = rp[N_NODES + n + 1];
  for (; e + 8 <= end; e += 8) {
    unsigned p[8]; unsigned s[8];
#pragma unroll
    for (int j = 0; j < 8; ++j) p[j] = ent[e + j];
#pragma unroll
    for (int j = 0; j < 8; ++j) s[j] = S2b[(p[j] >> 16) * NCLASS + cl];
    if (act) {
#pragma unroll
      for (int j = 0; j < 8; ++j) acc = fmaf(h2f_lo(p[j]), bf_lo(s[j]), acc);
    }
  }
  for (; e < end; ++e) {
    const unsigned p = ent[e];
    const unsigned s = S2b[(p >> 16) * NCLASS + cl];
    if (act) acc = fmaf(h2f_lo(p), bf_lo(s), acc);
  }
  const float v = act ? acc : -3.4e38f;
  float m = v;
#pragma unroll
  for (int off = 32; off; off >>= 1) m = fmaxf(m, __shfl_xor(m, off));
  float ex = act ? __expf(v - m) : 0.f;
  float s = ex;
#pragma unroll
  for (int off = 32; off; off >>= 1) s += __shfl_xor(s, off);
  const float lse = m + __logf(s);
  if (act) out[(size_t)n * NCLASS + lane] = v - lse;
}

extern "C" void kernel_launch(void* const* d_in, const int* in_sizes, int n_in,
                              void* d_out, int out_size, void* d_ws, size_t ws_size,
                              hipStream_t stream) {
  const float* x   = (const float*)d_in[0];
  const int*   ei1 = (const int*)d_in[2];
  const float* ew1 = (const float*)d_in[3];
  const int*   ei2 = (const int*)d_in[4];
  const float* ew2 = (const float*)d_in[5];
  const float* W1  = (const float*)d_in[6];
  const float* b1  = (const float*)d_in[7];
  const float* W2  = (const float*)d_in[8];
  const float* b2  = (const float*)d_in[9];
  float* out = (float*)d_out;

  // workspace (~55.7 MB). bkt dead after finalize; H1/S2b alias it.
  char* base = (char*)d_ws;
  int2*           bkt     = (int2*)base;                        // [0, 28.84M) 391*9216*8
  float*          H1      = (float*)base;                       // [0, 25.6M)  alias (after finalize)
  unsigned short* S2b     = (unsigned short*)(base + 25600000); // [25.6M, 29.6M) alias
  unsigned*       ent     = (unsigned*)(base + 29600000);       // [29.6M, 42.4M) packed {w16|src16}
  unsigned short* W1bT    = (unsigned short*)(base + 42400000); // 128KB (dead after gemm1)
  unsigned short* S1b     = (unsigned short*)(base + 42531072); // 12.8MB, 4 slabs [g][N][32]
  int*            row_ptr = (int*)(base + 55331072);            // (N_TOT+1)*4
  int*            bcur    = (int*)(base + 55731076);            // NBUCK*4
  int*            bptr    = (int*)(base + 55732640);            // NBUCK*4

  prep_w1_kernel<<<(NFEAT * NHID + 255) / 256, 256, 0, stream>>>(W1, W1bT);
  gemm1_kernel<<<(N_NODES + 127) / 128, 256, 0, stream>>>(x, W1bT, S1b);

  zero_bcur_kernel<<<1, 1024, 0, stream>>>(bcur);
  bucketize_kernel<<<(E_TOT / 8 + 1023) / 1024, 1024, 0, stream>>>(ei1, ew1, ei2, ew2, bcur, bkt);
  bucket_scan_kernel<<<1, 512, 0, stream>>>(bcur, bptr, row_ptr);
  finalize_kernel<<<NBUCK, NPB, 0, stream>>>(bkt, bcur, bptr, row_ptr, ent);

  agg1_kernel<<<4 * ((N_NODES + 15) / 16), 256, 0, stream>>>(row_ptr, ent, S1b, b1, H1);

  gemm2_kernel<<<(N_NODES + 7) / 8, 320, 0, stream>>>(H1, W2, S2b);
  agg2_lsm_kernel<<<(N_NODES + 3) / 4, 256, 0, stream>>>(row_ptr, ent, S2b, b2, out);
}